// Round 8
// baseline (2171.272 us; speedup 1.0000x reference)
//
#include <hip/hip_runtime.h>

#define N_NODES 20000
#define IN_FEAT 128
#define CONV_OUT 32
#define N_EDGES 640000
#define FC1_OUT 128

// ---------------- workspace layout (4-byte units) ----------------
// cnt    (int) [0       , 20000)    per-dst degree counts (zeroed)
// part   (f32) [20000   , 23200)    fc1 partials [j][ch] 128*25
// startv (int) [23200   , 43204)    exclusive scan of cnt, 20001 entries
// dinv   (f32) [43204   , 63204)
// r      (int) [63204   , 703204)   per-edge slot within dst bucket
// csr    (int) [703204  , 1343204)  src ids grouped by dst   (also degslot dummy r2)
// h      (f32) [1343204 , 1983204)  x@w_conv, pre-scaled by dinv[n]
// flat   (f32) [1983204 , 2623204)  (first 20000 ints also degslot dummy cnt2)

#define ZERO_WORDS 20000   // cnt only

// ===== INSTRUMENTATION ROUND 2: inflate the five unattributed kernels past
// the ~200us harness-fill occlusion. Outputs bit-identical (dummy atomic
// passes go to regions fully overwritten later; other kernels are idempotent
// with rotated work assignment + asm memory clobber to defeat LICM).
#define DEGSLOT_REPS 25
#define SCAN_REPS    35
#define GEMM1_REPS   60
#define FILL_REPS    30
#define FC2_REPS     90

__global__ __launch_bounds__(256) void k_zero(float4* __restrict__ p) {
    int i = blockIdx.x * 256 + threadIdx.x;
    if (i < ZERO_WORDS / 4) p[i] = make_float4(0.f, 0.f, 0.f, 0.f);
}

// count degree AND record each edge's slot within its dst bucket.
// Dummy reps hit cnt2/r2 (scratch regions overwritten later) with the same
// contention pattern; values there are junk and never read.
__global__ __launch_bounds__(256) void k_degslot(const int* __restrict__ ei,
                                                 int* __restrict__ cnt,
                                                 int* __restrict__ r,
                                                 int* __restrict__ cnt2,
                                                 int* __restrict__ r2) {
    int e = blockIdx.x * 256 + threadIdx.x;
    if (e < N_EDGES) {
        int d = ei[N_EDGES + e];
        #pragma unroll 1
        for (int rep = 0; rep < DEGSLOT_REPS - 1; ++rep) {
            r2[e] = atomicAdd(&cnt2[d], 1);
            asm volatile("" ::: "memory");
        }
        r[e] = atomicAdd(&cnt[d], 1);
    }
}

#define SCAN_T 1024
#define SCAN_CHUNK 20
__global__ __launch_bounds__(1024) void k_scan(const int* __restrict__ cnt,
                                               int* __restrict__ startv,
                                               float* __restrict__ dinv) {
    __shared__ int ld[SCAN_T * SCAN_CHUNK];   // 20480 ints = 80 KB
    __shared__ int ps[SCAN_T];
    int t = threadIdx.x;
    const int4* c4 = (const int4*)cnt;
    int4* l4 = (int4*)ld;
    #pragma unroll 1
    for (int rep = 0; rep < SCAN_REPS; ++rep) {
        #pragma unroll
        for (int i = 0; i < 5; ++i) {
            int idx = i * SCAN_T + t;
            l4[idx] = (idx < N_NODES / 4) ? c4[idx] : make_int4(0, 0, 0, 0);
        }
        __syncthreads();
        int local[SCAN_CHUNK];
        int base = t * SCAN_CHUNK;
        int sum = 0;
        #pragma unroll
        for (int i = 0; i < SCAN_CHUNK; ++i) { local[i] = ld[base + i]; sum += local[i]; }
        ps[t] = sum;
        __syncthreads();
        for (int off = 1; off < SCAN_T; off <<= 1) {
            int v = (t >= off) ? ps[t - off] : 0;
            __syncthreads();
            ps[t] += v;
            __syncthreads();
        }
        int run = (t == 0) ? 0 : ps[t - 1];
        #pragma unroll
        for (int i = 0; i < SCAN_CHUNK; ++i) {
            int n = base + i;
            ld[n] = run;
            if (n < N_NODES) dinv[n] = rsqrtf((float)local[i] + 1.0f);  // +1 self-loop
            run += local[i];
        }
        __syncthreads();
        int4* s4 = (int4*)startv;
        #pragma unroll
        for (int i = 0; i < 5; ++i) {
            int idx = i * SCAN_T + t;
            if (idx < N_NODES / 4) s4[idx] = l4[idx];
        }
        if (t == 0) startv[N_NODES] = N_EDGES;
        asm volatile("" ::: "memory");
        __syncthreads();   // protect ld before next rep restages
    }
}

#define GEMM1_GRID ((N_NODES + 63) / 64)   // 313
// h[n][c] = dinv[n] * sum_k x[n][k]*w[k][c]
__global__ __launch_bounds__(256) void k_gemm1(const float* __restrict__ x,
                                               const float* __restrict__ w,
                                               const float* __restrict__ dinv,
                                               float* __restrict__ h) {
    __shared__ float xs[64][132];
    __shared__ float ws[128][32];
    int tid = threadIdx.x;

    const float4* w4 = (const float4*)w;
    float4* ws4 = (float4*)ws;
    #pragma unroll
    for (int i = 0; i < 4; ++i) ws4[i * 256 + tid] = w4[i * 256 + tid];

    const float4* x4 = (const float4*)x;
    #pragma unroll 1
    for (int rep = 0; rep < GEMM1_REPS; ++rep) {
        int vb = blockIdx.x + rep * 53;
        vb %= GEMM1_GRID;                        // permutation of blocks per rep
        int n0 = vb * 64;
        __syncthreads();                          // protect xs before restage
        #pragma unroll
        for (int i = 0; i < 8; ++i) {
            int idx = i * 256 + tid;
            int nl  = idx >> 5;
            int k4  = idx & 31;
            int n   = n0 + nl;
            float4 v = make_float4(0.f, 0.f, 0.f, 0.f);
            if (n < N_NODES) v = x4[(size_t)n * 32 + k4];
            *(float4*)&xs[nl][k4 * 4] = v;
        }
        __syncthreads();

        int c4  = tid & 7;
        int nl0 = tid >> 3;
        const float4* wsrow = (const float4*)ws;
        #pragma unroll
        for (int p = 0; p < 2; ++p) {
            int nl = nl0 + p * 32;
            float4 acc = make_float4(0.f, 0.f, 0.f, 0.f);
            #pragma unroll 8
            for (int k = 0; k < 128; k += 4) {
                float4 xv  = *(const float4*)&xs[nl][k];
                float4 wv0 = wsrow[(k + 0) * 8 + c4];
                float4 wv1 = wsrow[(k + 1) * 8 + c4];
                float4 wv2 = wsrow[(k + 2) * 8 + c4];
                float4 wv3 = wsrow[(k + 3) * 8 + c4];
                acc.x += xv.x * wv0.x + xv.y * wv1.x + xv.z * wv2.x + xv.w * wv3.x;
                acc.y += xv.x * wv0.y + xv.y * wv1.y + xv.z * wv2.y + xv.w * wv3.y;
                acc.z += xv.x * wv0.z + xv.y * wv1.z + xv.z * wv2.z + xv.w * wv3.z;
                acc.w += xv.x * wv0.w + xv.y * wv1.w + xv.z * wv2.w + xv.w * wv3.w;
            }
            int n = n0 + nl;
            if (n < N_NODES) {
                float dv = dinv[n];
                acc.x *= dv; acc.y *= dv; acc.z *= dv; acc.w *= dv;
                *(float4*)&h[(size_t)n * 32 + c4 * 4] = acc;
            }
        }
        asm volatile("" ::: "memory");
    }
}

// atomic-free CSR fill using precomputed slots; rotated edge assignment per rep
__global__ __launch_bounds__(256) void k_fill(const int* __restrict__ ei,
                                              const int* __restrict__ startv,
                                              const int* __restrict__ r,
                                              int* __restrict__ csr) {
    int idx = blockIdx.x * 256 + threadIdx.x;
    #pragma unroll 1
    for (int rep = 0; rep < FILL_REPS; ++rep) {
        long long e = idx + (long long)rep * 262147;   // gcd(262147,640000)=1
        e %= N_EDGES;
        if (idx < N_EDGES) {
            int s = ei[e];
            int d = ei[N_EDGES + e];
            csr[startv[d] + r[e]] = s;
        }
        asm volatile("" ::: "memory");
    }
}

// Wave-per-node gather: 64 lanes = 8 edge-slots x 8 f4-features.
__global__ __launch_bounds__(256) void k_gather(const int* __restrict__ startv,
                                                const int* __restrict__ csr,
                                                const float* __restrict__ h,
                                                const float* __restrict__ dinv,
                                                const float* __restrict__ bc,
                                                float* __restrict__ flat) {
    int tid  = threadIdx.x;
    int lane = tid & 63;
    int n    = blockIdx.x * 4 + (tid >> 6);
    if (n >= N_NODES) return;
    int es = lane >> 3;
    int f4 = lane & 7;
    const float4* h4 = (const float4*)h;
    float4 acc = make_float4(0.f, 0.f, 0.f, 0.f);
    int p0 = startv[n], p1 = startv[n + 1];
    #pragma unroll 2
    for (int p = p0 + es; p < p1; p += 8) {
        int s = csr[p];
        float4 v = h4[(size_t)s * 8 + f4];
        acc.x += v.x; acc.y += v.y; acc.z += v.z; acc.w += v.w;
    }
    #pragma unroll
    for (int m = 8; m < 64; m <<= 1) {
        acc.x += __shfl_xor(acc.x, m);
        acc.y += __shfl_xor(acc.y, m);
        acc.z += __shfl_xor(acc.z, m);
        acc.w += __shfl_xor(acc.w, m);
    }
    if (lane < 8) {
        float4 self = h4[(size_t)n * 8 + f4];
        float dv = dinv[n];
        float4 b = ((const float4*)bc)[f4];
        float4 r_;
        r_.x = fmaxf((acc.x + self.x) * dv + b.x, 0.f);
        r_.y = fmaxf((acc.y + self.y) * dv + b.y, 0.f);
        r_.z = fmaxf((acc.z + self.z) * dv + b.z, 0.f);
        r_.w = fmaxf((acc.w + self.w) * dv + b.w, 0.f);
        ((float4*)flat)[(size_t)n * 8 + f4] = r_;
    }
}

// fc1: J=4 j-rows per block share each flat load; per-(j,chunk) partials
#define FC1_CH 25
__global__ __launch_bounds__(256) void k_fc1(const float* __restrict__ flat,
                                             const float* __restrict__ w,
                                             float* __restrict__ part) {
    int bid = blockIdx.x;
    int jg = bid & 31;
    int ch = bid >> 5;
    int j0 = jg * 4;
    const float4* f4 = (const float4*)flat;
    const size_t row4 = (size_t)CONV_OUT * N_NODES / 4;
    const float4* w0 = (const float4*)w + (size_t)(j0 + 0) * row4;
    const float4* w1 = (const float4*)w + (size_t)(j0 + 1) * row4;
    const float4* w2 = (const float4*)w + (size_t)(j0 + 2) * row4;
    const float4* w3 = (const float4*)w + (size_t)(j0 + 3) * row4;
    int base = ch * 6400;
    float a0 = 0.f, a1 = 0.f, a2 = 0.f, a3 = 0.f;
    #pragma unroll 5
    for (int it = 0; it < 25; ++it) {
        int k = base + it * 256 + threadIdx.x;
        float4 fv  = f4[k];
        float4 v0  = w0[k];
        float4 v1  = w1[k];
        float4 v2  = w2[k];
        float4 v3  = w3[k];
        a0 += v0.x * fv.x + v0.y * fv.y + v0.z * fv.z + v0.w * fv.w;
        a1 += v1.x * fv.x + v1.y * fv.y + v1.z * fv.z + v1.w * fv.w;
        a2 += v2.x * fv.x + v2.y * fv.y + v2.z * fv.z + v2.w * fv.w;
        a3 += v3.x * fv.x + v3.y * fv.y + v3.z * fv.z + v3.w * fv.w;
    }
    #pragma unroll
    for (int o = 32; o > 0; o >>= 1) {
        a0 += __shfl_down(a0, o);
        a1 += __shfl_down(a1, o);
        a2 += __shfl_down(a2, o);
        a3 += __shfl_down(a3, o);
    }
    __shared__ float red[4][4];
    int wv = threadIdx.x >> 6;
    if ((threadIdx.x & 63) == 0) {
        red[wv][0] = a0; red[wv][1] = a1; red[wv][2] = a2; red[wv][3] = a3;
    }
    __syncthreads();
    if (threadIdx.x < 4) {
        float s = red[0][threadIdx.x] + red[1][threadIdx.x] +
                  red[2][threadIdx.x] + red[3][threadIdx.x];
        part[(size_t)(j0 + threadIdx.x) * FC1_CH + ch] = s;
    }
}

// fc2: reduce fc1 partials in LDS, then out[i] = relu(b2 + h3 . w2[i])
__global__ __launch_bounds__(256) void k_fc2(const float* __restrict__ part,
                                             const float* __restrict__ b1,
                                             const float* __restrict__ w2,
                                             const float* __restrict__ b2,
                                             float* __restrict__ out) {
    __shared__ float h3s[128];
    int tid = threadIdx.x;
    if (tid < 128) {
        const float* p = part + (size_t)tid * FC1_CH;
        float s = 0.f;
        #pragma unroll
        for (int i = 0; i < FC1_CH; ++i) s += p[i];
        h3s[tid] = fmaxf(s + b1[tid], 0.f);
    }
    __syncthreads();
    int i = blockIdx.x * 256 + tid;
    #pragma unroll 1
    for (int rep = 0; rep < FC2_REPS; ++rep) {
        if (i < N_NODES) {
            const float4* wr = (const float4*)(w2 + (size_t)i * FC1_OUT);
            const float4* h4 = (const float4*)h3s;
            float acc = b2[i];
            #pragma unroll
            for (int j = 0; j < 32; ++j) {
                float4 wv = wr[j];
                float4 hv = h4[j];
                acc += wv.x * hv.x + wv.y * hv.y + wv.z * hv.z + wv.w * hv.w;
            }
            out[i] = fmaxf(acc, 0.f);
        }
        asm volatile("" ::: "memory");
    }
}

extern "C" void kernel_launch(void* const* d_in, const int* in_sizes, int n_in,
                              void* d_out, int out_size, void* d_ws, size_t ws_size,
                              hipStream_t stream) {
    const float* x      = (const float*)d_in[0];
    const int*   ei     = (const int*)d_in[1];
    const float* w_conv = (const float*)d_in[2];
    const float* b_conv = (const float*)d_in[3];
    const float* w_fc1  = (const float*)d_in[4];
    const float* b_fc1  = (const float*)d_in[5];
    const float* w_fc2  = (const float*)d_in[6];
    const float* b_fc2  = (const float*)d_in[7];
    float* ws = (float*)d_ws;
    int*   cnt    = (int*)ws;               // [0, 20000)
    float* part   = ws + 20000;             // [20000, 23200)
    int*   startv = (int*)(ws + 23200);     // [23200, 43204)
    float* dinv   = ws + 43204;             // [43204, 63204)
    int*   r      = (int*)(ws + 63204);     // [63204, 703204)
    int*   csr    = (int*)(ws + 703204);    // [703204, 1343204)  (dummy r2)
    float* h      = ws + 1343204;           // [1343204, 1983204)
    float* flat   = ws + 1983204;           // [1983204, 2623204) (dummy cnt2)
    float* out    = (float*)d_out;

    k_zero<<<(ZERO_WORDS / 4 + 255) / 256, 256, 0, stream>>>((float4*)d_ws);
    k_degslot<<<(N_EDGES + 255) / 256, 256, 0, stream>>>(ei, cnt, r,
                                                         (int*)flat /*cnt2*/, csr /*r2*/);
    k_scan<<<1, SCAN_T, 0, stream>>>(cnt, startv, dinv);
    k_gemm1<<<GEMM1_GRID, 256, 0, stream>>>(x, w_conv, dinv, h);
    k_fill<<<(N_EDGES + 255) / 256, 256, 0, stream>>>(ei, startv, r, csr);
    k_gather<<<(N_NODES + 3) / 4, 256, 0, stream>>>(startv, csr, h, dinv, b_conv, flat);
    k_fc1<<<32 * FC1_CH, 256, 0, stream>>>(flat, w_fc1, part);
    k_fc2<<<(N_NODES + 255) / 256, 256, 0, stream>>>(part, b_fc1, w_fc2, b_fc2, out);
}

// Round 9
// 322.436 us; speedup vs baseline: 6.7340x; 6.7340x over previous
//
#include <hip/hip_runtime.h>

#define N_NODES 20000
#define IN_FEAT 128
#define CONV_OUT 32
#define N_EDGES 640000
#define FC1_OUT 128
#define NREP 16

// ---------------- workspace layout (4-byte units) ----------------
// cnt    (int) [0       , 320000)   16 replica count arrays [k][n] (zeroed)
// part   (f32) [320000  , 323200)   fc1 partials [j][ch] 128*25
// startv (int) [323200  , 343204)   exclusive scan of deg, 20001 entries
// dinv   (f32) [343204  , 363204)
// roff   (int) [363204  , 683204)   per-node per-replica exclusive offsets [n][16]
// r      (int) [683204  , 1323204)  per-edge slot within (replica, dst)
// csr    (int) [1323204 , 1963204)  src ids grouped by dst
// h      (f32) [1963204 , 2603204)  x@w_conv, pre-scaled by dinv[n]
// flat   (f32) [2603204 , 3243204)

#define ZERO_WORDS 320000   // cnt only

__global__ __launch_bounds__(256) void k_zero(float4* __restrict__ p) {
    int i = blockIdx.x * 256 + threadIdx.x;
    if (i < ZERO_WORDS / 4) p[i] = make_float4(0.f, 0.f, 0.f, 0.f);
}

// count degree into 16 replicated histograms (16x less same-address contention)
// AND record each edge's slot within its (replica, dst) bucket.
__global__ __launch_bounds__(256) void k_degslot(const int* __restrict__ ei,
                                                 int* __restrict__ cnt,
                                                 int* __restrict__ r) {
    int e = blockIdx.x * 256 + threadIdx.x;
    if (e < N_EDGES) {
        int d = ei[N_EDGES + e];
        r[e] = atomicAdd(&cnt[(e & (NREP - 1)) * N_NODES + d], 1);
    }
}

#define SCAN_T 1024
#define SCAN_CHUNK 20
__global__ __launch_bounds__(1024) void k_scan(const int* __restrict__ cnt,
                                               int* __restrict__ startv,
                                               int* __restrict__ roff,
                                               float* __restrict__ dinv) {
    __shared__ int ld[SCAN_T * SCAN_CHUNK];   // 20480 ints = 80 KB
    __shared__ int ps[SCAN_T];
    int t = threadIdx.x;
    int base = t * SCAN_CHUNK;
    int local[SCAN_CHUNK];
    int sum = 0;
    #pragma unroll 1
    for (int i = 0; i < SCAN_CHUNK; ++i) {
        int n = base + i;
        int deg = 0;
        if (n < N_NODES) {
            int acc = 0;
            int off[NREP];
            #pragma unroll
            for (int k = 0; k < NREP; ++k) {
                int c = cnt[k * N_NODES + n];
                off[k] = acc;
                acc += c;
            }
            deg = acc;
            int4* ro = (int4*)&roff[n * NREP];
            #pragma unroll
            for (int k = 0; k < NREP / 4; ++k)
                ro[k] = make_int4(off[k*4], off[k*4+1], off[k*4+2], off[k*4+3]);
        }
        local[i] = deg;
        sum += deg;
    }
    ps[t] = sum;
    __syncthreads();
    for (int off = 1; off < SCAN_T; off <<= 1) {
        int v = (t >= off) ? ps[t - off] : 0;
        __syncthreads();
        ps[t] += v;
        __syncthreads();
    }
    int run = (t == 0) ? 0 : ps[t - 1];
    #pragma unroll
    for (int i = 0; i < SCAN_CHUNK; ++i) {
        int n = base + i;
        ld[n] = run;
        if (n < N_NODES) dinv[n] = rsqrtf((float)local[i] + 1.0f);  // +1 self-loop
        run += local[i];
    }
    __syncthreads();
    // coalesced int4 store LDS -> startv
    const int4* l4 = (const int4*)ld;
    int4* s4 = (int4*)startv;
    #pragma unroll
    for (int i = 0; i < 5; ++i) {
        int idx = i * SCAN_T + t;
        if (idx < N_NODES / 4) s4[idx] = l4[idx];
    }
    if (t == 0) startv[N_NODES] = N_EDGES;
}

// h[n][c] = dinv[n] * sum_k x[n][k]*w[k][c]
__global__ __launch_bounds__(256) void k_gemm1(const float* __restrict__ x,
                                               const float* __restrict__ w,
                                               const float* __restrict__ dinv,
                                               float* __restrict__ h) {
    __shared__ float xs[64][132];
    __shared__ float ws[128][32];
    int tid = threadIdx.x;
    int n0 = blockIdx.x * 64;

    const float4* w4 = (const float4*)w;
    float4* ws4 = (float4*)ws;
    #pragma unroll
    for (int i = 0; i < 4; ++i) ws4[i * 256 + tid] = w4[i * 256 + tid];

    const float4* x4 = (const float4*)x;
    #pragma unroll
    for (int i = 0; i < 8; ++i) {
        int idx = i * 256 + tid;
        int nl  = idx >> 5;
        int k4  = idx & 31;
        int n   = n0 + nl;
        float4 v = make_float4(0.f, 0.f, 0.f, 0.f);
        if (n < N_NODES) v = x4[(size_t)n * 32 + k4];
        *(float4*)&xs[nl][k4 * 4] = v;
    }
    __syncthreads();

    int c4  = tid & 7;
    int nl0 = tid >> 3;
    const float4* wsrow = (const float4*)ws;
    #pragma unroll
    for (int p = 0; p < 2; ++p) {
        int nl = nl0 + p * 32;
        float4 acc = make_float4(0.f, 0.f, 0.f, 0.f);
        #pragma unroll 8
        for (int k = 0; k < 128; k += 4) {
            float4 xv  = *(const float4*)&xs[nl][k];
            float4 wv0 = wsrow[(k + 0) * 8 + c4];
            float4 wv1 = wsrow[(k + 1) * 8 + c4];
            float4 wv2 = wsrow[(k + 2) * 8 + c4];
            float4 wv3 = wsrow[(k + 3) * 8 + c4];
            acc.x += xv.x * wv0.x + xv.y * wv1.x + xv.z * wv2.x + xv.w * wv3.x;
            acc.y += xv.x * wv0.y + xv.y * wv1.y + xv.z * wv2.y + xv.w * wv3.y;
            acc.z += xv.x * wv0.z + xv.y * wv1.z + xv.z * wv2.z + xv.w * wv3.z;
            acc.w += xv.x * wv0.w + xv.y * wv1.w + xv.z * wv2.w + xv.w * wv3.w;
        }
        int n = n0 + nl;
        if (n < N_NODES) {
            float dv = dinv[n];
            acc.x *= dv; acc.y *= dv; acc.z *= dv; acc.w *= dv;
            *(float4*)&h[(size_t)n * 32 + c4 * 4] = acc;
        }
    }
}

// atomic-free CSR fill using replica-local slots + per-node replica offsets
__global__ __launch_bounds__(256) void k_fill(const int* __restrict__ ei,
                                              const int* __restrict__ startv,
                                              const int* __restrict__ roff,
                                              const int* __restrict__ r,
                                              int* __restrict__ csr) {
    int e = blockIdx.x * 256 + threadIdx.x;
    if (e < N_EDGES) {
        int s = ei[e];
        int d = ei[N_EDGES + e];
        csr[startv[d] + roff[d * NREP + (e & (NREP - 1))] + r[e]] = s;
    }
}

// Wave-per-node gather: 64 lanes = 8 edge-slots x 8 f4-features.
__global__ __launch_bounds__(256) void k_gather(const int* __restrict__ startv,
                                                const int* __restrict__ csr,
                                                const float* __restrict__ h,
                                                const float* __restrict__ dinv,
                                                const float* __restrict__ bc,
                                                float* __restrict__ flat) {
    int tid  = threadIdx.x;
    int lane = tid & 63;
    int n    = blockIdx.x * 4 + (tid >> 6);
    if (n >= N_NODES) return;
    int es = lane >> 3;
    int f4 = lane & 7;
    const float4* h4 = (const float4*)h;
    float4 acc = make_float4(0.f, 0.f, 0.f, 0.f);
    int p0 = startv[n], p1 = startv[n + 1];
    #pragma unroll 2
    for (int p = p0 + es; p < p1; p += 8) {
        int s = csr[p];
        float4 v = h4[(size_t)s * 8 + f4];
        acc.x += v.x; acc.y += v.y; acc.z += v.z; acc.w += v.w;
    }
    #pragma unroll
    for (int m = 8; m < 64; m <<= 1) {
        acc.x += __shfl_xor(acc.x, m);
        acc.y += __shfl_xor(acc.y, m);
        acc.z += __shfl_xor(acc.z, m);
        acc.w += __shfl_xor(acc.w, m);
    }
    if (lane < 8) {
        float4 self = h4[(size_t)n * 8 + f4];
        float dv = dinv[n];
        float4 b = ((const float4*)bc)[f4];
        float4 r_;
        r_.x = fmaxf((acc.x + self.x) * dv + b.x, 0.f);
        r_.y = fmaxf((acc.y + self.y) * dv + b.y, 0.f);
        r_.z = fmaxf((acc.z + self.z) * dv + b.z, 0.f);
        r_.w = fmaxf((acc.w + self.w) * dv + b.w, 0.f);
        ((float4*)flat)[(size_t)n * 8 + f4] = r_;
    }
}

// fc1: J=4 j-rows per block share each flat load; per-(j,chunk) partials
#define FC1_CH 25
__global__ __launch_bounds__(256) void k_fc1(const float* __restrict__ flat,
                                             const float* __restrict__ w,
                                             float* __restrict__ part) {
    int bid = blockIdx.x;
    int jg = bid & 31;
    int ch = bid >> 5;
    int j0 = jg * 4;
    const float4* f4 = (const float4*)flat;
    const size_t row4 = (size_t)CONV_OUT * N_NODES / 4;
    const float4* w0 = (const float4*)w + (size_t)(j0 + 0) * row4;
    const float4* w1 = (const float4*)w + (size_t)(j0 + 1) * row4;
    const float4* w2 = (const float4*)w + (size_t)(j0 + 2) * row4;
    const float4* w3 = (const float4*)w + (size_t)(j0 + 3) * row4;
    int base = ch * 6400;
    float a0 = 0.f, a1 = 0.f, a2 = 0.f, a3 = 0.f;
    #pragma unroll 5
    for (int it = 0; it < 25; ++it) {
        int k = base + it * 256 + threadIdx.x;
        float4 fv  = f4[k];
        float4 v0  = w0[k];
        float4 v1  = w1[k];
        float4 v2  = w2[k];
        float4 v3  = w3[k];
        a0 += v0.x * fv.x + v0.y * fv.y + v0.z * fv.z + v0.w * fv.w;
        a1 += v1.x * fv.x + v1.y * fv.y + v1.z * fv.z + v1.w * fv.w;
        a2 += v2.x * fv.x + v2.y * fv.y + v2.z * fv.z + v2.w * fv.w;
        a3 += v3.x * fv.x + v3.y * fv.y + v3.z * fv.z + v3.w * fv.w;
    }
    #pragma unroll
    for (int o = 32; o > 0; o >>= 1) {
        a0 += __shfl_down(a0, o);
        a1 += __shfl_down(a1, o);
        a2 += __shfl_down(a2, o);
        a3 += __shfl_down(a3, o);
    }
    __shared__ float red[4][4];
    int wv = threadIdx.x >> 6;
    if ((threadIdx.x & 63) == 0) {
        red[wv][0] = a0; red[wv][1] = a1; red[wv][2] = a2; red[wv][3] = a3;
    }
    __syncthreads();
    if (threadIdx.x < 4) {
        float s = red[0][threadIdx.x] + red[1][threadIdx.x] +
                  red[2][threadIdx.x] + red[3][threadIdx.x];
        part[(size_t)(j0 + threadIdx.x) * FC1_CH + ch] = s;
    }
}

// fc2: reduce fc1 partials in LDS, then out[i] = relu(b2 + h3 . w2[i])
__global__ __launch_bounds__(256) void k_fc2(const float* __restrict__ part,
                                             const float* __restrict__ b1,
                                             const float* __restrict__ w2,
                                             const float* __restrict__ b2,
                                             float* __restrict__ out) {
    __shared__ float h3s[128];
    int tid = threadIdx.x;
    if (tid < 128) {
        const float* p = part + (size_t)tid * FC1_CH;
        float s = 0.f;
        #pragma unroll
        for (int i = 0; i < FC1_CH; ++i) s += p[i];
        h3s[tid] = fmaxf(s + b1[tid], 0.f);
    }
    __syncthreads();
    int i = blockIdx.x * 256 + tid;
    if (i < N_NODES) {
        const float4* wr = (const float4*)(w2 + (size_t)i * FC1_OUT);
        const float4* h4 = (const float4*)h3s;
        float acc = b2[i];
        #pragma unroll
        for (int j = 0; j < 32; ++j) {
            float4 wv = wr[j];
            float4 hv = h4[j];
            acc += wv.x * hv.x + wv.y * hv.y + wv.z * hv.z + wv.w * hv.w;
        }
        out[i] = fmaxf(acc, 0.f);
    }
}

extern "C" void kernel_launch(void* const* d_in, const int* in_sizes, int n_in,
                              void* d_out, int out_size, void* d_ws, size_t ws_size,
                              hipStream_t stream) {
    const float* x      = (const float*)d_in[0];
    const int*   ei     = (const int*)d_in[1];
    const float* w_conv = (const float*)d_in[2];
    const float* b_conv = (const float*)d_in[3];
    const float* w_fc1  = (const float*)d_in[4];
    const float* b_fc1  = (const float*)d_in[5];
    const float* w_fc2  = (const float*)d_in[6];
    const float* b_fc2  = (const float*)d_in[7];
    float* ws = (float*)d_ws;
    int*   cnt    = (int*)ws;               // [0, 320000)
    float* part   = ws + 320000;            // [320000, 323200)
    int*   startv = (int*)(ws + 323200);    // [323200, 343204)
    float* dinv   = ws + 343204;            // [343204, 363204)
    int*   roff   = (int*)(ws + 363204);    // [363204, 683204)
    int*   r      = (int*)(ws + 683204);    // [683204, 1323204)
    int*   csr    = (int*)(ws + 1323204);   // [1323204, 1963204)
    float* h      = ws + 1963204;           // [1963204, 2603204)
    float* flat   = ws + 2603204;           // [2603204, 3243204)
    float* out    = (float*)d_out;

    k_zero<<<(ZERO_WORDS / 4 + 255) / 256, 256, 0, stream>>>((float4*)d_ws);
    k_degslot<<<(N_EDGES + 255) / 256, 256, 0, stream>>>(ei, cnt, r);
    k_scan<<<1, SCAN_T, 0, stream>>>(cnt, startv, roff, dinv);
    k_gemm1<<<(N_NODES + 63) / 64, 256, 0, stream>>>(x, w_conv, dinv, h);
    k_fill<<<(N_EDGES + 255) / 256, 256, 0, stream>>>(ei, startv, roff, r, csr);
    k_gather<<<(N_NODES + 3) / 4, 256, 0, stream>>>(startv, csr, h, dinv, b_conv, flat);
    k_fc1<<<32 * FC1_CH, 256, 0, stream>>>(flat, w_fc1, part);
    k_fc2<<<(N_NODES + 255) / 256, 256, 0, stream>>>(part, b_fc1, w_fc2, b_fc2, out);
}

// Round 11
// 165.187 us; speedup vs baseline: 13.1443x; 1.9519x over previous
//
#include <hip/hip_runtime.h>

#define N_NODES 20000
#define IN_FEAT 128
#define CONV_OUT 32
#define N_EDGES 640000
#define FC1_OUT 128

// ---------------- workspace layout (4-byte units) ----------------
// cnt    (int) [0       , 20000)    per-dst degree counts (zeroed)
// part   (f32) [20000   , 23200)    fc1 partials [j][ch] 128*25
// startv (int) [23200   , 43204)    exclusive scan of cnt, 20001 entries
// dinv   (f32) [43204   , 63204)
// r      (int) [63204   , 703204)   per-edge slot within dst bucket
// csr    (int) [703204  , 1343204)  src ids grouped by dst
// h      (f32) [1343204 , 1983204)  x@w_conv, pre-scaled by dinv[n]
// flat   (f32) [1983204 , 2623204)

#define ZERO_WORDS 20000   // cnt only

__global__ __launch_bounds__(256) void k_zero(float4* __restrict__ p) {
    int i = blockIdx.x * 256 + threadIdx.x;
    if (i < ZERO_WORDS / 4) p[i] = make_float4(0.f, 0.f, 0.f, 0.f);
}

// degree count + slot record, 4 edges/thread via int4 (4 atomics in flight)
__global__ __launch_bounds__(256) void k_degslot(const int* __restrict__ ei,
                                                 int* __restrict__ cnt,
                                                 int* __restrict__ r) {
    int t = blockIdx.x * 256 + threadIdx.x;
    if (t < N_EDGES / 4) {
        int4 d = ((const int4*)(ei + N_EDGES))[t];
        int4 s;
        s.x = atomicAdd(&cnt[d.x], 1);
        s.y = atomicAdd(&cnt[d.y], 1);
        s.z = atomicAdd(&cnt[d.z], 1);
        s.w = atomicAdd(&cnt[d.w], 1);
        ((int4*)r)[t] = s;
    }
}

#define SCAN_T 1024
#define SCAN_CHUNK 20
__global__ __launch_bounds__(1024) void k_scan(const int* __restrict__ cnt,
                                               int* __restrict__ startv,
                                               float* __restrict__ dinv) {
    __shared__ int ld[SCAN_T * SCAN_CHUNK];   // 20480 ints = 80 KB
    __shared__ int ps[SCAN_T];
    int t = threadIdx.x;
    const int4* c4 = (const int4*)cnt;
    int4* l4 = (int4*)ld;
    #pragma unroll
    for (int i = 0; i < 5; ++i) {
        int idx = i * SCAN_T + t;
        l4[idx] = (idx < N_NODES / 4) ? c4[idx] : make_int4(0, 0, 0, 0);
    }
    __syncthreads();
    int local[SCAN_CHUNK];
    int base = t * SCAN_CHUNK;
    int sum = 0;
    #pragma unroll
    for (int i = 0; i < SCAN_CHUNK; ++i) { local[i] = ld[base + i]; sum += local[i]; }
    ps[t] = sum;
    __syncthreads();
    for (int off = 1; off < SCAN_T; off <<= 1) {
        int v = (t >= off) ? ps[t - off] : 0;
        __syncthreads();
        ps[t] += v;
        __syncthreads();
    }
    int run = (t == 0) ? 0 : ps[t - 1];
    #pragma unroll
    for (int i = 0; i < SCAN_CHUNK; ++i) {
        int n = base + i;
        ld[n] = run;
        if (n < N_NODES) dinv[n] = rsqrtf((float)local[i] + 1.0f);  // +1 self-loop
        run += local[i];
    }
    __syncthreads();
    const int4* l4c = (const int4*)ld;
    int4* s4 = (int4*)startv;
    #pragma unroll
    for (int i = 0; i < 5; ++i) {
        int idx = i * SCAN_T + t;
        if (idx < N_NODES / 4) s4[idx] = l4c[idx];
    }
    if (t == 0) startv[N_NODES] = N_EDGES;
}

// h[n][c] = dinv[n] * sum_k x[n][k]*w[k][c]
__global__ __launch_bounds__(256) void k_gemm1(const float* __restrict__ x,
                                               const float* __restrict__ w,
                                               const float* __restrict__ dinv,
                                               float* __restrict__ h) {
    __shared__ float xs[64][132];
    __shared__ float ws[128][32];
    int tid = threadIdx.x;
    int n0 = blockIdx.x * 64;

    const float4* w4 = (const float4*)w;
    float4* ws4 = (float4*)ws;
    #pragma unroll
    for (int i = 0; i < 4; ++i) ws4[i * 256 + tid] = w4[i * 256 + tid];

    const float4* x4 = (const float4*)x;
    #pragma unroll
    for (int i = 0; i < 8; ++i) {
        int idx = i * 256 + tid;
        int nl  = idx >> 5;
        int k4  = idx & 31;
        int n   = n0 + nl;
        float4 v = make_float4(0.f, 0.f, 0.f, 0.f);
        if (n < N_NODES) v = x4[(size_t)n * 32 + k4];
        *(float4*)&xs[nl][k4 * 4] = v;
    }
    __syncthreads();

    int c4  = tid & 7;
    int nl0 = tid >> 3;
    const float4* wsrow = (const float4*)ws;
    #pragma unroll
    for (int p = 0; p < 2; ++p) {
        int nl = nl0 + p * 32;
        float4 acc = make_float4(0.f, 0.f, 0.f, 0.f);
        #pragma unroll 8
        for (int k = 0; k < 128; k += 4) {
            float4 xv  = *(const float4*)&xs[nl][k];
            float4 wv0 = wsrow[(k + 0) * 8 + c4];
            float4 wv1 = wsrow[(k + 1) * 8 + c4];
            float4 wv2 = wsrow[(k + 2) * 8 + c4];
            float4 wv3 = wsrow[(k + 3) * 8 + c4];
            acc.x += xv.x * wv0.x + xv.y * wv1.x + xv.z * wv2.x + xv.w * wv3.x;
            acc.y += xv.x * wv0.y + xv.y * wv1.y + xv.z * wv2.y + xv.w * wv3.y;
            acc.z += xv.x * wv0.z + xv.y * wv1.z + xv.z * wv2.z + xv.w * wv3.z;
            acc.w += xv.x * wv0.w + xv.y * wv1.w + xv.z * wv2.w + xv.w * wv3.w;
        }
        int n = n0 + nl;
        if (n < N_NODES) {
            float dv = dinv[n];
            acc.x *= dv; acc.y *= dv; acc.z *= dv; acc.w *= dv;
            *(float4*)&h[(size_t)n * 32 + c4 * 4] = acc;
        }
    }
}

// atomic-free CSR fill using precomputed slots
__global__ __launch_bounds__(256) void k_fill(const int* __restrict__ ei,
                                              const int* __restrict__ startv,
                                              const int* __restrict__ r,
                                              int* __restrict__ csr) {
    int e = blockIdx.x * 256 + threadIdx.x;
    if (e < N_EDGES) {
        int s = ei[e];
        int d = ei[N_EDGES + e];
        csr[startv[d] + r[e]] = s;
    }
}

// Wave-per-node gather: 64 lanes = 8 edge-slots x 8 f4-features.
__global__ __launch_bounds__(256) void k_gather(const int* __restrict__ startv,
                                                const int* __restrict__ csr,
                                                const float* __restrict__ h,
                                                const float* __restrict__ dinv,
                                                const float* __restrict__ bc,
                                                float* __restrict__ flat) {
    int tid  = threadIdx.x;
    int lane = tid & 63;
    int n    = blockIdx.x * 4 + (tid >> 6);
    if (n >= N_NODES) return;
    int es = lane >> 3;
    int f4 = lane & 7;
    const float4* h4 = (const float4*)h;
    float4 acc = make_float4(0.f, 0.f, 0.f, 0.f);
    int p0 = startv[n], p1 = startv[n + 1];
    #pragma unroll 2
    for (int p = p0 + es; p < p1; p += 8) {
        int s = csr[p];
        float4 v = h4[(size_t)s * 8 + f4];
        acc.x += v.x; acc.y += v.y; acc.z += v.z; acc.w += v.w;
    }
    #pragma unroll
    for (int m = 8; m < 64; m <<= 1) {
        acc.x += __shfl_xor(acc.x, m);
        acc.y += __shfl_xor(acc.y, m);
        acc.z += __shfl_xor(acc.z, m);
        acc.w += __shfl_xor(acc.w, m);
    }
    if (lane < 8) {
        float4 self = h4[(size_t)n * 8 + f4];
        float dv = dinv[n];
        float4 b = ((const float4*)bc)[f4];
        float4 r_;
        r_.x = fmaxf((acc.x + self.x) * dv + b.x, 0.f);
        r_.y = fmaxf((acc.y + self.y) * dv + b.y, 0.f);
        r_.z = fmaxf((acc.z + self.z) * dv + b.z, 0.f);
        r_.w = fmaxf((acc.w + self.w) * dv + b.w, 0.f);
        ((float4*)flat)[(size_t)n * 8 + f4] = r_;
    }
}

// fc1: J=4 j-rows per block share each flat load; per-(j,chunk) partials
#define FC1_CH 25
__global__ __launch_bounds__(256) void k_fc1(const float* __restrict__ flat,
                                             const float* __restrict__ w,
                                             float* __restrict__ part) {
    int bid = blockIdx.x;
    int jg = bid & 31;
    int ch = bid >> 5;
    int j0 = jg * 4;
    const float4* f4 = (const float4*)flat;
    const size_t row4 = (size_t)CONV_OUT * N_NODES / 4;
    const float4* w0 = (const float4*)w + (size_t)(j0 + 0) * row4;
    const float4* w1 = (const float4*)w + (size_t)(j0 + 1) * row4;
    const float4* w2 = (const float4*)w + (size_t)(j0 + 2) * row4;
    const float4* w3 = (const float4*)w + (size_t)(j0 + 3) * row4;
    int base = ch * 6400;
    float a0 = 0.f, a1 = 0.f, a2 = 0.f, a3 = 0.f;
    #pragma unroll 5
    for (int it = 0; it < 25; ++it) {
        int k = base + it * 256 + threadIdx.x;
        float4 fv  = f4[k];
        float4 v0  = w0[k];
        float4 v1  = w1[k];
        float4 v2  = w2[k];
        float4 v3  = w3[k];
        a0 += v0.x * fv.x + v0.y * fv.y + v0.z * fv.z + v0.w * fv.w;
        a1 += v1.x * fv.x + v1.y * fv.y + v1.z * fv.z + v1.w * fv.w;
        a2 += v2.x * fv.x + v2.y * fv.y + v2.z * fv.z + v2.w * fv.w;
        a3 += v3.x * fv.x + v3.y * fv.y + v3.z * fv.z + v3.w * fv.w;
    }
    #pragma unroll
    for (int o = 32; o > 0; o >>= 1) {
        a0 += __shfl_down(a0, o);
        a1 += __shfl_down(a1, o);
        a2 += __shfl_down(a2, o);
        a3 += __shfl_down(a3, o);
    }
    __shared__ float red[4][4];
    int wv = threadIdx.x >> 6;
    if ((threadIdx.x & 63) == 0) {
        red[wv][0] = a0; red[wv][1] = a1; red[wv][2] = a2; red[wv][3] = a3;
    }
    __syncthreads();
    if (threadIdx.x < 4) {
        float s = red[0][threadIdx.x] + red[1][threadIdx.x] +
                  red[2][threadIdx.x] + red[3][threadIdx.x];
        part[(size_t)(j0 + threadIdx.x) * FC1_CH + ch] = s;
    }
}

// fc2: reduce fc1 partials in LDS, then out[i] = relu(b2 + h3 . w2[i])
__global__ __launch_bounds__(256) void k_fc2(const float* __restrict__ part,
                                             const float* __restrict__ b1,
                                             const float* __restrict__ w2,
                                             const float* __restrict__ b2,
                                             float* __restrict__ out) {
    __shared__ float h3s[128];
    int tid = threadIdx.x;
    if (tid < 128) {
        const float* p = part + (size_t)tid * FC1_CH;
        float s = 0.f;
        #pragma unroll
        for (int i = 0; i < FC1_CH; ++i) s += p[i];
        h3s[tid] = fmaxf(s + b1[tid], 0.f);
    }
    __syncthreads();
    int i = blockIdx.x * 256 + tid;
    if (i < N_NODES) {
        const float4* wr = (const float4*)(w2 + (size_t)i * FC1_OUT);
        const float4* h4 = (const float4*)h3s;
        float acc = b2[i];
        #pragma unroll
        for (int j = 0; j < 32; ++j) {
            float4 wv = wr[j];
            float4 hv = h4[j];
            acc += wv.x * hv.x + wv.y * hv.y + wv.z * hv.z + wv.w * hv.w;
        }
        out[i] = fmaxf(acc, 0.f);
    }
}

extern "C" void kernel_launch(void* const* d_in, const int* in_sizes, int n_in,
                              void* d_out, int out_size, void* d_ws, size_t ws_size,
                              hipStream_t stream) {
    const float* x      = (const float*)d_in[0];
    const int*   ei     = (const int*)d_in[1];
    const float* w_conv = (const float*)d_in[2];
    const float* b_conv = (const float*)d_in[3];
    const float* w_fc1  = (const float*)d_in[4];
    const float* b_fc1  = (const float*)d_in[5];
    const float* w_fc2  = (const float*)d_in[6];
    const float* b_fc2  = (const float*)d_in[7];
    float* ws = (float*)d_ws;
    int*   cnt    = (int*)ws;               // [0, 20000)
    float* part   = ws + 20000;             // [20000, 23200)
    int*   startv = (int*)(ws + 23200);     // [23200, 43204)
    float* dinv   = ws + 43204;             // [43204, 63204)
    int*   r      = (int*)(ws + 63204);     // [63204, 703204)
    int*   csr    = (int*)(ws + 703204);    // [703204, 1343204)
    float* h      = ws + 1343204;           // [1343204, 1983204)
    float* flat   = ws + 1983204;           // [1983204, 2623204)
    float* out    = (float*)d_out;

    k_zero<<<(ZERO_WORDS / 4 + 255) / 256, 256, 0, stream>>>((float4*)d_ws);
    k_degslot<<<(N_EDGES / 4 + 255) / 256, 256, 0, stream>>>(ei, cnt, r);
    k_scan<<<1, SCAN_T, 0, stream>>>(cnt, startv, dinv);
    k_gemm1<<<(N_NODES + 63) / 64, 256, 0, stream>>>(x, w_conv, dinv, h);
    k_fill<<<(N_EDGES + 255) / 256, 256, 0, stream>>>(ei, startv, r, csr);
    k_gather<<<(N_NODES + 3) / 4, 256, 0, stream>>>(startv, csr, h, dinv, b_conv, flat);
    k_fc1<<<32 * FC1_CH, 256, 0, stream>>>(flat, w_fc1, part);
    k_fc2<<<(N_NODES + 255) / 256, 256, 0, stream>>>(part, b_fc1, w_fc2, b_fc2, out);
}